// Round 4
// baseline (150.956 us; speedup 1.0000x reference)
//
#include <hip/hip_runtime.h>
#include <math.h>

#define BB 128   // batch
#define TT 8     // seq
#define DD 2048  // model dim
#define RR 4     // TT rank
#define VV 512   // vocab

typedef __attribute__((ext_vector_type(8))) short short8;
typedef __attribute__((ext_vector_type(4))) float v4f;

// ---------------- phase A: T-mean -> fmb(bf16), alpha/beta half-partials, zero marg ----------------
__global__ __launch_bounds__(256) void phaseA(const float* __restrict__ inp,
                                              const float* __restrict__ w_alpha,
                                              const float* __restrict__ w_beta,
                                              unsigned short* __restrict__ fmb,
                                              float* __restrict__ alphaP,
                                              float* __restrict__ betaP,
                                              float* __restrict__ marg) {
    int bid = blockIdx.x;
    int b = bid >> 1, half = bid & 1;
    int tid = threadIdx.x;
    if (bid == 0) {
#pragma unroll
        for (int e = 0; e < 8; ++e) marg[e * 256 + tid] = 0.f;
    }
    const float* base = inp + (size_t)b * TT * DD;
    float pa[4] = {0.f, 0.f, 0.f, 0.f};
    float pb[4] = {0.f, 0.f, 0.f, 0.f};
#pragma unroll
    for (int i = 0; i < 4; ++i) {
        int d = half * 1024 + i * 256 + tid;
        float s = 0.f;
#pragma unroll
        for (int t = 0; t < TT; ++t) s += base[t * DD + d];
        float v = s * (1.0f / TT);
        union { float f; unsigned u; } cv; cv.f = v;
        unsigned r = cv.u + 0x7fffu + ((cv.u >> 16) & 1u);   // RNE
        fmb[b * DD + d] = (unsigned short)(r >> 16);
        float4 wa = *(const float4*)(w_alpha + d * 4);
        float4 wb = *(const float4*)(w_beta + d * 4);
        pa[0] += v * wa.x; pa[1] += v * wa.y; pa[2] += v * wa.z; pa[3] += v * wa.w;
        pb[0] += v * wb.x; pb[1] += v * wb.y; pb[2] += v * wb.z; pb[3] += v * wb.w;
    }
#pragma unroll
    for (int r = 0; r < 4; ++r) {
        for (int m = 1; m < 64; m <<= 1) {
            pa[r] += __shfl_xor(pa[r], m);
            pb[r] += __shfl_xor(pb[r], m);
        }
    }
    __shared__ float red[4][8];
    if ((tid & 63) == 0) {
        int w = tid >> 6;
#pragma unroll
        for (int r = 0; r < 4; ++r) { red[w][r] = pa[r]; red[w][4 + r] = pb[r]; }
    }
    __syncthreads();
    if (tid < 8) {
        float s = red[0][tid] + red[1][tid] + red[2][tid] + red[3][tid];
        if (tid < 4) alphaP[(half * BB + b) * 4 + tid] = s;
        else         betaP[(half * BB + b) * 4 + (tid - 4)] = s;
    }
}

// ---------------- phase B: barrier-free bf16 MFMA GEMM + fused epilogue ----------------
// 256 blocks x 512 thr. Block nb: cols [nb*32, +32). Wave w: col-half (w&1),
// row-half ((w>>1)&1)*64, K-half (w>>2)*1024. B-frags gathered directly from wv
// (8 dword loads/iter, truncate-packed to bf16); A-frags direct from L2-resident fmb.
// NO barriers in the K-loop; one __syncthreads to combine K-halves via LDS.
__global__ __launch_bounds__(512) void phaseB(const unsigned short* __restrict__ fmb,
                                              const float* __restrict__ wv,
                                              const int* __restrict__ labels,
                                              float* __restrict__ marg,
                                              float* __restrict__ sel) {
    __shared__ float xch[4][4][64][4];   // [src wave 4..7][tile][lane][elem] = 16 KB
    __shared__ int slab[BB * TT];

    const int tid = threadIdx.x;
    slab[tid] = labels[tid];
    slab[tid + 512] = labels[tid + 512];

    const int nb = blockIdx.x;
    const int w = tid >> 6, lane = tid & 63;
    const int m15 = lane & 15, q = lane >> 4;
    const int ch = w & 1;          // col-half
    const int rh = (w >> 1) & 1;   // row-half
    const int kh = w >> 2;         // K-half
    const int colg = nb * 32 + ch * 16 + m15;

    v4f acc[4];
#pragma unroll
    for (int t = 0; t < 4; ++t) acc[t] = (v4f){0.f, 0.f, 0.f, 0.f};

    const float* wvp = wv + (size_t)(kh * 1024 + q * 8) * 8192 + colg;
    const unsigned short* ap = fmb + (size_t)(rh * 64 + m15) * DD + kh * 1024 + q * 8;

#pragma unroll 2
    for (int kc = 0; kc < 32; ++kc) {
        float f[8];
#pragma unroll
        for (int j = 0; j < 8; ++j) f[j] = wvp[(size_t)j * 8192];
        short8 bf;
        unsigned* bu = (unsigned*)&bf;
#pragma unroll
        for (int p = 0; p < 4; ++p) {
            union { float ff; unsigned u; } x0, x1;
            x0.ff = f[2 * p]; x1.ff = f[2 * p + 1];
            bu[p] = (x0.u >> 16) | (x1.u & 0xffff0000u);   // truncate-pack bf16x2
        }
#pragma unroll
        for (int tile = 0; tile < 4; ++tile) {
            short8 af = *(const short8*)(ap + tile * 16 * DD);
            acc[tile] = __builtin_amdgcn_mfma_f32_16x16x32_bf16(af, bf, acc[tile], 0, 0, 0);
        }
        wvp += (size_t)32 * 8192;
        ap += 32;
    }

    // combine K-halves: waves 4-7 hand off to waves 0-3
    if (kh == 1) {
#pragma unroll
        for (int tile = 0; tile < 4; ++tile)
            *(v4f*)&xch[w - 4][tile][lane][0] = acc[tile];
    }
    __syncthreads();
    if (kh == 1) return;
#pragma unroll
    for (int tile = 0; tile < 4; ++tile)
        acc[tile] += *(const v4f*)&xch[w][tile][lane][0];

    // epilogue: |acc| -> marg atomics + label-select scatter. C layout: row=q*4+r, col=m15.
    const int i4 = (nb >> 6) * 4;                       // i*4
    const int jj = m15 & 3;                             // j
    const int v = (nb & 63) * 8 + ch * 4 + (m15 >> 2);  // vocab id of this lane's col
#pragma unroll
    for (int tile = 0; tile < 4; ++tile) {
#pragma unroll
        for (int r = 0; r < 4; ++r) {
            int m = rh * 64 + tile * 16 + q * 4 + r;
            float a = fabsf(acc[tile][r]);
            float s = a + __shfl_xor(a, 4);
            s += __shfl_xor(s, 8);
            if (m15 < 4) atomicAdd(&marg[m * 16 + i4 + m15], s);
#pragma unroll
            for (int t = 0; t < TT; ++t) {
                if (slab[m * 8 + t] == v) sel[(m * 8 + t) * 16 + i4 + jj] = a;
            }
        }
    }
}

// ---------------- phase D: chain products, normalizer, loss ----------------
__global__ __launch_bounds__(128) void phaseD(const float* __restrict__ alphaP,
                                              const float* __restrict__ betaP,
                                              const float* __restrict__ marg,
                                              const float* __restrict__ sel,
                                              float* __restrict__ out) {
    int b = threadIdx.x;
    float alpha[4], beta[4];
#pragma unroll
    for (int r = 0; r < 4; ++r) {
        alpha[r] = fabsf(alphaP[b * 4 + r] + alphaP[512 + b * 4 + r]);
        beta[r]  = fabsf(betaP[b * 4 + r] + betaP[512 + b * 4 + r]);
    }
    const float* sb = sel + b * TT * 16;
    float res[16], tmp[16], mm[16], zm[16];
#pragma unroll
    for (int ee = 0; ee < 16; ++ee) res[ee] = sb[ee];
    for (int t = 1; t < TT; ++t) {
        const float* m = sb + t * 16;
#pragma unroll
        for (int i = 0; i < 4; ++i)
#pragma unroll
            for (int jj = 0; jj < 4; ++jj) {
                float s = 0.f;
#pragma unroll
                for (int k = 0; k < 4; ++k) s += res[i * 4 + k] * m[k * 4 + jj];
                tmp[i * 4 + jj] = s;
            }
#pragma unroll
        for (int ee = 0; ee < 16; ++ee) res[ee] = tmp[ee];
    }
#pragma unroll
    for (int ee = 0; ee < 16; ++ee) { mm[ee] = marg[b * 16 + ee]; zm[ee] = mm[ee]; }
    for (int st = 0; st < TT; ++st) {
#pragma unroll
        for (int i = 0; i < 4; ++i)
#pragma unroll
            for (int jj = 0; jj < 4; ++jj) {
                float s = 0.f;
#pragma unroll
                for (int k = 0; k < 4; ++k) s += zm[i * 4 + k] * mm[k * 4 + jj];
                tmp[i * 4 + jj] = s;
            }
#pragma unroll
        for (int ee = 0; ee < 16; ++ee) zm[ee] = tmp[ee];
    }
    float u = 0.f, z = 0.f;
#pragma unroll
    for (int i = 0; i < 4; ++i) {
#pragma unroll
        for (int jj = 0; jj < 4; ++jj) {
            u += alpha[i] * res[i * 4 + jj] * beta[jj];
            z += alpha[i] * zm[i * 4 + jj] * beta[jj];
        }
    }
    float loss = logf(z) - logf(u);
    __shared__ float red[128];
    red[b] = loss;
    __syncthreads();
    for (int off = 64; off >= 1; off >>= 1) {
        if (b < off) red[b] += red[b + off];
        __syncthreads();
    }
    if (b == 0) out[0] = red[0] * (1.0f / BB);
}

extern "C" void kernel_launch(void* const* d_in, const int* in_sizes, int n_in,
                              void* d_out, int out_size, void* d_ws, size_t ws_size,
                              hipStream_t stream) {
    const float* inp     = (const float*)d_in[0];  // [128,8,2048]
    const int*   labels  = (const int*)d_in[1];    // [128,8]
    const float* w_alpha = (const float*)d_in[2];  // [2048,4]
    const float* w_beta  = (const float*)d_in[3];  // [2048,4]
    const float* wv      = (const float*)d_in[4];  // [2048,8192]
    float* out = (float*)d_out;

    float* ws     = (float*)d_ws;
    float* alphaP = ws;                        // [2][128][4]  = 1024
    float* betaP  = ws + 1024;                 // [2][128][4]  = 1024
    float* marg   = ws + 2048;                 // [128][16]    = 2048
    float* sel    = ws + 4096;                 // [128][8][16] = 16384
    unsigned short* fmb = (unsigned short*)(ws + 20480);  // [128][2048] bf16

    phaseA<<<256, 256, 0, stream>>>(inp, w_alpha, w_beta, fmb, alphaP, betaP, marg);
    phaseB<<<256, 512, 0, stream>>>(fmb, wv, labels, marg, sel);
    phaseD<<<1, 128, 0, stream>>>(alphaP, betaP, marg, sel, out);
}